// Round 3
// baseline (546.652 us; speedup 1.0000x reference)
//
#include <hip/hip_runtime.h>

// StrictLowerTriQSM: f_{i+1} = a_i @ f_i + outer(q_i, x_i), y_i = p_i @ f_i
// N=500000, M=8, K=16. Blocked associative scan, 4 kernels.
// Round 2: k1/k3 use per-wave double-buffered LDS staging via
// global_load_lds (groups of 8 elements) + counted vmcnt waits, replacing
// the serial s_load-latency chain. CHUNK 62->64.

#define NTOT 500000
#define CHUNK 64
#define NCHUNK 8192            // 8192*64 = 524288 >= 500000
#define GRPSZ 64
#define NGRP 128               // 8192/64
#define WAVES_PER_BLOCK 4

// workspace float offsets (column-major: [c][col][row])
#define OFF_AGGA  0u           // NCHUNK*64  = 524288
#define OFF_AGGB  524288u      // NCHUNK*128 = 1048576
#define OFF_GAGA  1572864u     // NGRP*64    = 8192
#define OFF_GAGB  1581056u     // NGRP*128   = 16384
// total = 1597440 floats = 6.39 MB

#define AS1(p) ((const __attribute__((address_space(1))) void*)(p))
#define AS3(p) ((__attribute__((address_space(3))) void*)(p))
#define GLOAD_LDS16(gp, lp) __builtin_amdgcn_global_load_lds(AS1(gp), AS3(lp), 16, 0, 0)
#define GLOAD_LDS4(gp, lp)  __builtin_amdgcn_global_load_lds(AS1(gp), AS3(lp), 4, 0, 0)

// ---------------- Phase 1: per-chunk aggregates (A_blk, B_blk) -------------
// One wave per chunk. Lanes 0..15 own B columns, lanes 16..23 own A columns.
// a,q staged per-wave into double-buffered LDS in groups of 8 elements.
__global__ __launch_bounds__(256) void k1_aggregate(
    const float* __restrict__ q, const float* __restrict__ a,
    const float* __restrict__ x, float* __restrict__ ws)
{
  // per wave: 2 buffers x (a 512 + q 64) floats = 2*576; 4 waves
  __shared__ float sm[4 * 2 * 576];   // 18432 B
  const int wid  = __builtin_amdgcn_readfirstlane((int)(threadIdx.x >> 6));
  const int c    = blockIdx.x * WAVES_PER_BLOCK + wid;
  const int lane = (int)(threadIdx.x & 63);
  const bool isB = lane < 16;
  const bool isA = (lane >= 16) && (lane < 24);
  const int bcol = lane & 15;
  const int acol = (lane - 16) & 7;

  float* wb0 = sm + (wid * 2 + 0) * 576;
  float* wb1 = sm + (wid * 2 + 1) * 576;

  float v[8];
#pragma unroll
  for (int m = 0; m < 8; ++m) v[m] = 0.f;
  if (isA) v[acol] = 1.f;           // A starts as identity

  const int start = c * CHUNK;
  int cnt = NTOT - start;
  cnt = cnt < 0 ? 0 : (cnt > CHUNK ? CHUNK : cnt);
  const int ngr = cnt >> 3;          // cnt is always 0, 32 or 64

  auto stage = [&](int g, float* lb) {
    const size_t i0 = (size_t)(start + g * 8);
    const float* ga = a + i0 * 64u;
    GLOAD_LDS16(ga + lane * 4, lb);             // elements 0..3  (1024 B)
    GLOAD_LDS16(ga + 256 + lane * 4, lb + 256); // elements 4..7  (1024 B)
    GLOAD_LDS4(q + i0 * 8u + lane, lb + 512);   // q for 8 elems  (256 B)
  };

  if (ngr > 0) stage(0, wb0);
  for (int g = 0; g < ngr; ++g) {
    float* lb = (g & 1) ? wb1 : wb0;
    if (g + 1 < ngr) {
      stage(g + 1, (g & 1) ? wb0 : wb1);
      asm volatile("s_waitcnt vmcnt(3)" ::: "memory");   // keep next-group loads in flight
    } else {
      asm volatile("s_waitcnt vmcnt(0)" ::: "memory");
    }
#pragma unroll
    for (int e = 0; e < 8; ++e) {
      const int i = start + g * 8 + e;
      const float xk = x[(size_t)i * 16u + bcol];
      const float* ae = lb + e * 64;
      float qv[8];
      *(float4*)&qv[0] = *(const float4*)(lb + 512 + e * 8);
      *(float4*)&qv[4] = *(const float4*)(lb + 512 + e * 8 + 4);
      float nv[8];
#pragma unroll
      for (int m = 0; m < 8; ++m) {
        float4 r0 = *(const float4*)(ae + m * 8);
        float4 r1 = *(const float4*)(ae + m * 8 + 4);
        float s = isB ? (qv[m] * xk) : 0.f;
        s += r0.x * v[0] + r0.y * v[1] + r0.z * v[2] + r0.w * v[3]
           + r1.x * v[4] + r1.y * v[5] + r1.z * v[6] + r1.w * v[7];
        nv[m] = s;
      }
#pragma unroll
      for (int m = 0; m < 8; ++m) v[m] = nv[m];
    }
  }

  if (isB) {
    float* dst = ws + OFF_AGGB + (size_t)c * 128u + (size_t)bcol * 8u;
#pragma unroll
    for (int m = 0; m < 8; ++m) dst[m] = v[m];
  } else if (isA) {
    float* dst = ws + OFF_AGGA + (size_t)c * 64u + (size_t)acol * 8u;
#pragma unroll
    for (int m = 0; m < 8; ++m) dst[m] = v[m];
  }
}

// ---------- Phase 2a: serial scan inside each group of 64 chunks -----------
// IN-PLACE: reads the chunk aggregate, overwrites the slot with the
// group-local EXCLUSIVE prefix, accumulates the group aggregate.
__global__ __launch_bounds__(64) void k2a_groupscan(float* __restrict__ ws)
{
  const int g    = blockIdx.x;
  const int lane = (int)(threadIdx.x & 63);
  const bool isB = lane < 16;
  const bool isA = (lane >= 16) && (lane < 24);
  const int bcol = lane & 15;
  const int acol = (lane - 16) & 7;

  float v[8];
#pragma unroll
  for (int m = 0; m < 8; ++m) v[m] = 0.f;
  if (isA) v[acol] = 1.f;           // run = identity

  for (int j = 0; j < GRPSZ; ++j) {
    const int c = g * GRPSZ + j;
    const float* __restrict__ aA = ws + OFF_AGGA + (size_t)c * 64u;
    float af[64];                    // af[t*8+m] = Ac[m][t] (col-major)
#pragma unroll
    for (int t = 0; t < 64; ++t) af[t] = aA[t];
    float bB[8];
    if (isB) {
      const float* __restrict__ src =
          ws + OFF_AGGB + (size_t)c * 128u + (size_t)bcol * 8u;
#pragma unroll
      for (int m = 0; m < 8; ++m) bB[m] = src[m];
    }
    // overwrite slot with the exclusive prefix (= current run)
    if (isB) {
      float* dst = ws + OFF_AGGB + (size_t)c * 128u + (size_t)bcol * 8u;
#pragma unroll
      for (int m = 0; m < 8; ++m) dst[m] = v[m];
    } else if (isA) {
      float* dst = ws + OFF_AGGA + (size_t)c * 64u + (size_t)acol * 8u;
#pragma unroll
      for (int m = 0; m < 8; ++m) dst[m] = v[m];
    }
    // run = agg_c ∘ run : (Ac@Arun, Ac@Brun + Bc)
    float nv[8];
#pragma unroll
    for (int m = 0; m < 8; ++m) {
      float s = 0.f;
#pragma unroll
      for (int t = 0; t < 8; ++t) s += af[t * 8 + m] * v[t];
      nv[m] = s;
    }
    if (isB) {
#pragma unroll
      for (int m = 0; m < 8; ++m) nv[m] += bB[m];
    }
#pragma unroll
    for (int m = 0; m < 8; ++m) v[m] = nv[m];
  }

  if (isB) {
    float* dst = ws + OFF_GAGB + (size_t)g * 128u + (size_t)bcol * 8u;
#pragma unroll
    for (int m = 0; m < 8; ++m) dst[m] = v[m];
  } else if (isA) {
    float* dst = ws + OFF_GAGA + (size_t)g * 64u + (size_t)acol * 8u;
#pragma unroll
    for (int m = 0; m < 8; ++m) dst[m] = v[m];
  }
}

// ---------- Phase 2b: single-wave scan over the NGRP group aggregates ------
// IN-PLACE on GAGB: overwrites each group's B aggregate with the
// group-EXCLUSIVE B prefix (all phase 3 needs). GAGA is read-only.
__global__ __launch_bounds__(64) void k2b_topscan(float* __restrict__ ws)
{
  const int lane = (int)(threadIdx.x & 63);
  const bool isB = lane < 16;
  const bool isA = (lane >= 16) && (lane < 24);
  const int bcol = lane & 15;
  const int acol = (lane - 16) & 7;

  float v[8];
#pragma unroll
  for (int m = 0; m < 8; ++m) v[m] = 0.f;
  if (isA) v[acol] = 1.f;

  for (int g = 0; g < NGRP; ++g) {
    const float* __restrict__ aA = ws + OFF_GAGA + (size_t)g * 64u;
    float af[64];
#pragma unroll
    for (int t = 0; t < 64; ++t) af[t] = aA[t];
    float bB[8];
    if (isB) {
      const float* __restrict__ src =
          ws + OFF_GAGB + (size_t)g * 128u + (size_t)bcol * 8u;
#pragma unroll
      for (int m = 0; m < 8; ++m) bB[m] = src[m];
      float* dst = ws + OFF_GAGB + (size_t)g * 128u + (size_t)bcol * 8u;
#pragma unroll
      for (int m = 0; m < 8; ++m) dst[m] = v[m];
    }
    float nv[8];
#pragma unroll
    for (int m = 0; m < 8; ++m) {
      float s = 0.f;
#pragma unroll
      for (int t = 0; t < 8; ++t) s += af[t * 8 + m] * v[t];
      nv[m] = s;
    }
    if (isB) {
#pragma unroll
      for (int m = 0; m < 8; ++m) nv[m] += bB[m];
    }
#pragma unroll
    for (int m = 0; m < 8; ++m) v[m] = nv[m];
  }
}

// ---------- Phase 3: replay each chunk from its carry, emit y --------------
// f0(chunk) = prefA_c @ grpPrefB_g + prefB_c ; then the plain recurrence.
// y_i = p_i @ f_i uses the PRE-update carry (scan emits carry before update).
__global__ __launch_bounds__(256) void k3_output(
    const float* __restrict__ p, const float* __restrict__ q,
    const float* __restrict__ a, const float* __restrict__ x,
    const float* __restrict__ ws, float* __restrict__ out)
{
  // per wave: 2 buffers x (a 512 + q 64 + p 64) floats = 2*640; 4 waves
  __shared__ float sm3[4 * 2 * 640];  // 20480 B
  const int wid  = __builtin_amdgcn_readfirstlane((int)(threadIdx.x >> 6));
  const int c    = blockIdx.x * WAVES_PER_BLOCK + wid;
  const int lane = (int)(threadIdx.x & 63);
  const int k    = lane & 15;          // all 64 lanes mirror k<16 work
  const bool active = lane < 16;
  const int g    = c >> 6;             // GRPSZ = 64

  float* wb0 = sm3 + (wid * 2 + 0) * 640;
  float* wb1 = sm3 + (wid * 2 + 1) * 640;

  // init f column k = prefA_c @ grpB_g[:,k] + prefB_c[:,k]
  const float* __restrict__ pA = ws + OFF_AGGA + (size_t)c * 64u;
  float af[64];
#pragma unroll
  for (int t = 0; t < 64; ++t) af[t] = pA[t];     // af[t*8+m] = prefA[m][t]
  const float* __restrict__ gBp = ws + OFF_GAGB + (size_t)g * 128u + (size_t)k * 8u;
  const float* __restrict__ lBp = ws + OFF_AGGB + (size_t)c * 128u + (size_t)k * 8u;
  float gcol[8];
#pragma unroll
  for (int t = 0; t < 8; ++t) gcol[t] = gBp[t];
  float f[8];
#pragma unroll
  for (int m = 0; m < 8; ++m) {
    float s = lBp[m];
#pragma unroll
    for (int t = 0; t < 8; ++t) s += af[t * 8 + m] * gcol[t];
    f[m] = s;
  }

  const int start = c * CHUNK;
  int cnt = NTOT - start;
  cnt = cnt < 0 ? 0 : (cnt > CHUNK ? CHUNK : cnt);
  const int ngr = cnt >> 3;

  auto stage = [&](int gg, float* lb) {
    const size_t i0 = (size_t)(start + gg * 8);
    const float* ga = a + i0 * 64u;
    GLOAD_LDS16(ga + lane * 4, lb);
    GLOAD_LDS16(ga + 256 + lane * 4, lb + 256);
    GLOAD_LDS4(q + i0 * 8u + lane, lb + 512);
    GLOAD_LDS4(p + i0 * 8u + lane, lb + 576);
  };

  if (ngr > 0) stage(0, wb0);
  for (int gg = 0; gg < ngr; ++gg) {
    float* lb = (gg & 1) ? wb1 : wb0;
    if (gg + 1 < ngr) {
      stage(gg + 1, (gg & 1) ? wb0 : wb1);
      asm volatile("s_waitcnt vmcnt(4)" ::: "memory");
    } else {
      asm volatile("s_waitcnt vmcnt(0)" ::: "memory");
    }
#pragma unroll
    for (int e = 0; e < 8; ++e) {
      const int i = start + gg * 8 + e;
      const float xk = x[(size_t)i * 16u + k];
      const float* ae = lb + e * 64;
      float qv[8], pv[8];
      *(float4*)&qv[0] = *(const float4*)(lb + 512 + e * 8);
      *(float4*)&qv[4] = *(const float4*)(lb + 512 + e * 8 + 4);
      *(float4*)&pv[0] = *(const float4*)(lb + 576 + e * 8);
      *(float4*)&pv[4] = *(const float4*)(lb + 576 + e * 8 + 4);

      float y = 0.f;
#pragma unroll
      for (int m = 0; m < 8; ++m) y += pv[m] * f[m];
      if (active) out[(size_t)i * 16u + k] = y;

      float nf[8];
#pragma unroll
      for (int m = 0; m < 8; ++m) {
        float4 r0 = *(const float4*)(ae + m * 8);
        float4 r1 = *(const float4*)(ae + m * 8 + 4);
        float s = qv[m] * xk;
        s += r0.x * f[0] + r0.y * f[1] + r0.z * f[2] + r0.w * f[3]
           + r1.x * f[4] + r1.y * f[5] + r1.z * f[6] + r1.w * f[7];
        nf[m] = s;
      }
#pragma unroll
      for (int m = 0; m < 8; ++m) f[m] = nf[m];
    }
  }
}

extern "C" void kernel_launch(void* const* d_in, const int* in_sizes, int n_in,
                              void* d_out, int out_size, void* d_ws, size_t ws_size,
                              hipStream_t stream)
{
  const float* p = (const float*)d_in[0];
  const float* q = (const float*)d_in[1];
  const float* a = (const float*)d_in[2];
  const float* x = (const float*)d_in[3];
  float* out = (float*)d_out;
  float* ws  = (float*)d_ws;

  dim3 blk(256);
  dim3 grid1(NCHUNK / WAVES_PER_BLOCK);   // 2048 blocks, 4 waves each
  hipLaunchKernelGGL(k1_aggregate, grid1, blk, 0, stream, q, a, x, ws);
  hipLaunchKernelGGL(k2a_groupscan, dim3(NGRP), dim3(64), 0, stream, ws);
  hipLaunchKernelGGL(k2b_topscan, dim3(1), dim3(64), 0, stream, ws);
  hipLaunchKernelGGL(k3_output, grid1, blk, 0, stream, p, q, a, x, ws, out);
}

// Round 4
// 196.632 us; speedup vs baseline: 2.7801x; 2.7801x over previous
//
#include <hip/hip_runtime.h>

// StrictLowerTriQSM: f_{i+1} = a_i @ f_i + outer(q_i, x_i), y_i = p_i @ f_i
// N=500000, M=8, K=16. Blocked associative scan, 4 kernels.
// Round 4: chunk-packed waves (k1: 2 chunks/wave, k3: 4 chunks/wave, all
// data LDS-staged, unroll-1 bodies to cap VGPR), LDS-staged k2a/k2b with
// register-pipelined B operands.

#define NTOT 500000
#define CHUNK 64
#define NCHUNK 8192            // 8192*64 = 524288 >= 500000
#define G 4                    // elements per staging group
#define NGPC 16                // groups per chunk
#define GRPSZ 64
#define NGRP 128               // 8192/64
#define CLAMPI 499996          // NTOT - G

// workspace float offsets (COLUMN-major tiles: [c][col][row])
#define OFF_AGGA  0u           // NCHUNK*64  = 524288
#define OFF_AGGB  524288u      // NCHUNK*128 = 1048576
#define OFF_GAGA  1572864u     // NGRP*64    = 8192
#define OFF_GAGB  1581056u     // NGRP*128   = 16384

#define AS1(p) ((const __attribute__((address_space(1))) void*)(p))
#define AS3(p) ((__attribute__((address_space(3))) void*)(p))
#define GLOAD_LDS16(gp, lp) __builtin_amdgcn_global_load_lds(AS1(gp), AS3(lp), 16, 0, 0)
#define GLOAD_LDS4(gp, lp)  __builtin_amdgcn_global_load_lds(AS1(gp), AS3(lp), 4, 0, 0)
#define WAIT_VM(n) asm volatile("s_waitcnt vmcnt(" #n ")" ::: "memory")

static __device__ __forceinline__ int iminc(int a, int b) { return a < b ? a : b; }

// ---------------- Phase 1: per-chunk aggregates (A_blk, B_blk) -------------
// 2 chunks per wave: lanes [0..31] -> chunk 2w, [32..63] -> chunk 2w+1.
// Within a 32-lane half: ll<16 = B columns, 16<=ll<24 = A columns.
// Per-wave double-buffered LDS: [buf][A 2x256 | q 64 | x 128] = 704 floats.
__global__ __launch_bounds__(256, 4) void k1_aggregate(
    const float* __restrict__ q, const float* __restrict__ a,
    const float* __restrict__ x, float* __restrict__ ws)
{
  __shared__ float sm[4 * 2 * 704];   // 22528 B
  const int wv   = (int)(threadIdx.x >> 6);
  const int wave = blockIdx.x * 4 + wv;          // 0..4095
  const int lane = (int)(threadIdx.x & 63);
  const int sub  = lane >> 5;                    // which chunk of the pair
  const int ll   = lane & 31;
  const int c    = wave * 2 + sub;               // this lane's chunk
  const bool isB = ll < 16;
  const bool isA = (ll >= 16) && (ll < 24);
  const int bcol = ll & 15;
  const int acol = (ll - 16) & 7;

  float* wbuf = sm + wv * 1408;
  const int c0 = wave * 2, c1 = c0 + 1;

  float v[8];
#pragma unroll
  for (int m = 0; m < 8; ++m) v[m] = 0.f;
  if (isA) v[acol] = 1.f;                        // A starts as identity

  int cnt = NTOT - c * CHUNK;
  cnt = cnt < 0 ? 0 : (cnt > CHUNK ? CHUNK : cnt);

  auto stage = [&](int g, float* lb) {
    const int b0 = iminc(c0 * CHUNK + g * G, CLAMPI);
    const int b1 = iminc(c1 * CHUNK + g * G, CLAMPI);
    GLOAD_LDS16(a + (size_t)b0 * 64u + lane * 4, lb);        // chunk0 A (256 f)
    GLOAD_LDS16(a + (size_t)b1 * 64u + lane * 4, lb + 256);  // chunk1 A
    GLOAD_LDS4(q + (size_t)(lane < 32 ? b0 : b1) * 8u + ll, lb + 512); // q (64 f)
    GLOAD_LDS4(x + (size_t)b0 * 16u + lane, lb + 576);       // chunk0 x (64 f)
    GLOAD_LDS4(x + (size_t)b1 * 16u + lane, lb + 640);       // chunk1 x
  };

  stage(0, wbuf);
#pragma unroll 1
  for (int g = 0; g < NGPC; ++g) {
    float* lb = wbuf + (g & 1) * 704;
    if (g + 1 < NGPC) {
      stage(g + 1, wbuf + ((g + 1) & 1) * 704);
      WAIT_VM(5);
    } else {
      WAIT_VM(0);
    }
#pragma unroll 1
    for (int e = 0; e < G; ++e) {
      const int eg = g * G + e;
      if (eg < cnt) {
        const float* ae = lb + sub * 256 + e * 64;   // row-major a[m][t]
        const float xk  = lb[576 + sub * 64 + e * 16 + bcol];
        const float* qe = lb + 512 + sub * 32 + e * 8;
        float qv[8];
        *(float4*)&qv[0] = *(const float4*)(qe);
        *(float4*)&qv[4] = *(const float4*)(qe + 4);
        float nv[8];
#pragma unroll
        for (int m = 0; m < 8; ++m) {
          float4 r0 = *(const float4*)(ae + m * 8);
          float4 r1 = *(const float4*)(ae + m * 8 + 4);
          float s = isB ? (qv[m] * xk) : 0.f;
          s += r0.x * v[0] + r0.y * v[1] + r0.z * v[2] + r0.w * v[3]
             + r1.x * v[4] + r1.y * v[5] + r1.z * v[6] + r1.w * v[7];
          nv[m] = s;
        }
#pragma unroll
        for (int m = 0; m < 8; ++m) v[m] = nv[m];
      }
    }
  }

  if (isB) {
    float* dst = ws + OFF_AGGB + (size_t)c * 128u + (size_t)bcol * 8u;
#pragma unroll
    for (int m = 0; m < 8; ++m) dst[m] = v[m];
  } else if (isA) {
    float* dst = ws + OFF_AGGA + (size_t)c * 64u + (size_t)acol * 8u;
#pragma unroll
    for (int m = 0; m < 8; ++m) dst[m] = v[m];
  }
}

// ---------- Phase 2a: serial scan inside each group of 64 chunks -----------
// A-tiles staged to LDS up front (pipelined global_load_lds); B operands
// software-prefetched one combine ahead. IN-PLACE: slot <- exclusive prefix.
__global__ __launch_bounds__(64) void k2a_groupscan(float* __restrict__ ws)
{
  __shared__ float sA[GRPSZ * 64];   // 16 KiB
  const int g    = blockIdx.x;
  const int lane = (int)(threadIdx.x & 63);
  const bool isB = lane < 16;
  const bool isA = (lane >= 16) && (lane < 24);
  const int bcol = lane & 15;
  const int acol = (lane - 16) & 7;

#pragma unroll 1
  for (int t = 0; t < 16; ++t)
    GLOAD_LDS16(ws + OFF_AGGA + (size_t)g * (GRPSZ * 64u) + t * 256 + lane * 4,
                sA + t * 256);

  float v[8];
#pragma unroll
  for (int m = 0; m < 8; ++m) v[m] = 0.f;
  if (isA) v[acol] = 1.f;

  // prefetch B of combine 0
  float4 nb0, nb1;
  {
    const float* s = ws + OFF_AGGB + (size_t)(g * GRPSZ) * 128u + (size_t)bcol * 8u;
    nb0 = *(const float4*)s; nb1 = *(const float4*)(s + 4);
  }
  WAIT_VM(0);   // LDS staging complete (B prefetch handled by compiler waits)

#pragma unroll 1
  for (int j = 0; j < GRPSZ; ++j) {
    const int c = g * GRPSZ + j;
    float bB[8] = {nb0.x, nb0.y, nb0.z, nb0.w, nb1.x, nb1.y, nb1.z, nb1.w};
    if (j + 1 < GRPSZ) {
      const float* s = ws + OFF_AGGB + (size_t)(c + 1) * 128u + (size_t)bcol * 8u;
      nb0 = *(const float4*)s; nb1 = *(const float4*)(s + 4);
    }
    // overwrite slot with the exclusive prefix (= current run)
    if (isB) {
      float* dst = ws + OFF_AGGB + (size_t)c * 128u + (size_t)bcol * 8u;
#pragma unroll
      for (int m = 0; m < 8; ++m) dst[m] = v[m];
    } else if (isA) {
      float* dst = ws + OFF_AGGA + (size_t)c * 64u + (size_t)acol * 8u;
#pragma unroll
      for (int m = 0; m < 8; ++m) dst[m] = v[m];
    }
    // run = agg_c ∘ run : (Ac@Arun, Ac@Brun + Bc). sA tile is column-major.
    const float* Aj = sA + j * 64;
    float nv[8];
#pragma unroll
    for (int m = 0; m < 8; ++m) nv[m] = 0.f;
#pragma unroll
    for (int t = 0; t < 8; ++t) {
      float4 col0 = *(const float4*)(Aj + t * 8);
      float4 col1 = *(const float4*)(Aj + t * 8 + 4);
      nv[0] += col0.x * v[t]; nv[1] += col0.y * v[t];
      nv[2] += col0.z * v[t]; nv[3] += col0.w * v[t];
      nv[4] += col1.x * v[t]; nv[5] += col1.y * v[t];
      nv[6] += col1.z * v[t]; nv[7] += col1.w * v[t];
    }
    if (isB) {
#pragma unroll
      for (int m = 0; m < 8; ++m) nv[m] += bB[m];
    }
#pragma unroll
    for (int m = 0; m < 8; ++m) v[m] = nv[m];
  }

  if (isB) {
    float* dst = ws + OFF_GAGB + (size_t)g * 128u + (size_t)bcol * 8u;
#pragma unroll
    for (int m = 0; m < 8; ++m) dst[m] = v[m];
  } else if (isA) {
    float* dst = ws + OFF_GAGA + (size_t)g * 64u + (size_t)acol * 8u;
#pragma unroll
    for (int m = 0; m < 8; ++m) dst[m] = v[m];
  }
}

// ---------- Phase 2b: single-wave scan over the NGRP group aggregates ------
// GAGA staged to LDS; B prefetched. IN-PLACE on GAGB: slot <- exclusive B.
__global__ __launch_bounds__(64) void k2b_topscan(float* __restrict__ ws)
{
  __shared__ float sA[NGRP * 64];    // 32 KiB
  const int lane = (int)(threadIdx.x & 63);
  const bool isB = lane < 16;
  const bool isA = (lane >= 16) && (lane < 24);
  const int bcol = lane & 15;
  const int acol = (lane - 16) & 7;

#pragma unroll 1
  for (int t = 0; t < 32; ++t)
    GLOAD_LDS16(ws + OFF_GAGA + t * 256 + lane * 4, sA + t * 256);

  float v[8];
#pragma unroll
  for (int m = 0; m < 8; ++m) v[m] = 0.f;
  if (isA) v[acol] = 1.f;

  float4 nb0, nb1;
  {
    const float* s = ws + OFF_GAGB + (size_t)bcol * 8u;
    nb0 = *(const float4*)s; nb1 = *(const float4*)(s + 4);
  }
  WAIT_VM(0);

#pragma unroll 1
  for (int j = 0; j < NGRP; ++j) {
    float bB[8] = {nb0.x, nb0.y, nb0.z, nb0.w, nb1.x, nb1.y, nb1.z, nb1.w};
    if (j + 1 < NGRP) {
      const float* s = ws + OFF_GAGB + (size_t)(j + 1) * 128u + (size_t)bcol * 8u;
      nb0 = *(const float4*)s; nb1 = *(const float4*)(s + 4);
    }
    if (isB) {
      float* dst = ws + OFF_GAGB + (size_t)j * 128u + (size_t)bcol * 8u;
#pragma unroll
      for (int m = 0; m < 8; ++m) dst[m] = v[m];
    }
    const float* Aj = sA + j * 64;
    float nv[8];
#pragma unroll
    for (int m = 0; m < 8; ++m) nv[m] = 0.f;
#pragma unroll
    for (int t = 0; t < 8; ++t) {
      float4 col0 = *(const float4*)(Aj + t * 8);
      float4 col1 = *(const float4*)(Aj + t * 8 + 4);
      nv[0] += col0.x * v[t]; nv[1] += col0.y * v[t];
      nv[2] += col0.z * v[t]; nv[3] += col0.w * v[t];
      nv[4] += col1.x * v[t]; nv[5] += col1.y * v[t];
      nv[6] += col1.z * v[t]; nv[7] += col1.w * v[t];
    }
    if (isB) {
#pragma unroll
      for (int m = 0; m < 8; ++m) nv[m] += bB[m];
    }
#pragma unroll
    for (int m = 0; m < 8; ++m) v[m] = nv[m];
  }
}

// ---------- Phase 3: replay each chunk from its carry, emit y --------------
// 4 chunks per wave: lane sub = lane>>4 picks the chunk, k = lane&15 the
// f-column. All 64 lanes active. Per-wave double-buffered LDS:
// [A 4x260 | q 132 | p 132 | x 4x80] = 1624 floats per buffer.
#define K3_BQ 1040
#define K3_BP 1172
#define K3_BX 1304
#define K3_BUF 1624
__global__ __launch_bounds__(256, 3) void k3_output(
    const float* __restrict__ p, const float* __restrict__ q,
    const float* __restrict__ a, const float* __restrict__ x,
    const float* __restrict__ ws, float* __restrict__ out)
{
  __shared__ float sm3[4 * 2 * K3_BUF];   // 51968 B
  const int wv   = (int)(threadIdx.x >> 6);
  const int wave = blockIdx.x * 4 + wv;          // 0..2047
  const int lane = (int)(threadIdx.x & 63);
  const int sub  = lane >> 4;                    // chunk 0..3 of the quad
  const int k    = lane & 15;                    // f column
  const int c    = wave * 4 + sub;
  const int grp  = c >> 6;                       // GRPSZ = 64

  float* wbuf = sm3 + wv * (2 * K3_BUF);
  const int cb = wave * 4;

  auto stage = [&](int g, float* lb) {
    int b[4];
#pragma unroll
    for (int cc = 0; cc < 4; ++cc) b[cc] = iminc((cb + cc) * CHUNK + g * G, CLAMPI);
    GLOAD_LDS16(a + (size_t)b[0] * 64u + lane * 4, lb);
    GLOAD_LDS16(a + (size_t)b[1] * 64u + lane * 4, lb + 260);
    GLOAD_LDS16(a + (size_t)b[2] * 64u + lane * 4, lb + 520);
    GLOAD_LDS16(a + (size_t)b[3] * 64u + lane * 4, lb + 780);
    GLOAD_LDS4(q + (size_t)(lane < 32 ? b[0] : b[1]) * 8u + (lane & 31), lb + K3_BQ);
    GLOAD_LDS4(q + (size_t)(lane < 32 ? b[2] : b[3]) * 8u + (lane & 31), lb + K3_BQ + 68);
    GLOAD_LDS4(p + (size_t)(lane < 32 ? b[0] : b[1]) * 8u + (lane & 31), lb + K3_BP);
    GLOAD_LDS4(p + (size_t)(lane < 32 ? b[2] : b[3]) * 8u + (lane & 31), lb + K3_BP + 68);
    GLOAD_LDS4(x + (size_t)b[0] * 16u + lane, lb + K3_BX);
    GLOAD_LDS4(x + (size_t)b[1] * 16u + lane, lb + K3_BX + 80);
    GLOAD_LDS4(x + (size_t)b[2] * 16u + lane, lb + K3_BX + 160);
    GLOAD_LDS4(x + (size_t)b[3] * 16u + lane, lb + K3_BX + 240);
  };

  stage(0, wbuf);   // issue first, hide under the f-init below

  // init f column k = prefA_c @ grpB[:,k] + prefB_c[:,k]  (ws is col-major)
  const float* __restrict__ pA = ws + OFF_AGGA + (size_t)c * 64u;
  float af[64];
#pragma unroll
  for (int t = 0; t < 64; ++t) af[t] = pA[t];     // af[t*8+m] = prefA[m][t]
  const float* __restrict__ gBp = ws + OFF_GAGB + (size_t)grp * 128u + (size_t)k * 8u;
  const float* __restrict__ lBp = ws + OFF_AGGB + (size_t)c * 128u + (size_t)k * 8u;
  float gcol[8];
#pragma unroll
  for (int t = 0; t < 8; ++t) gcol[t] = gBp[t];
  float f[8];
#pragma unroll
  for (int m = 0; m < 8; ++m) {
    float s = lBp[m];
#pragma unroll
    for (int t = 0; t < 8; ++t) s += af[t * 8 + m] * gcol[t];
    f[m] = s;
  }

  int cnt = NTOT - c * CHUNK;
  cnt = cnt < 0 ? 0 : (cnt > CHUNK ? CHUNK : cnt);

#pragma unroll 1
  for (int g = 0; g < NGPC; ++g) {
    float* lb = wbuf + (g & 1) * K3_BUF;
    if (g + 1 < NGPC) {
      stage(g + 1, wbuf + ((g + 1) & 1) * K3_BUF);
      WAIT_VM(12);
    } else {
      WAIT_VM(0);
    }
#pragma unroll 1
    for (int e = 0; e < G; ++e) {
      const int eg = g * G + e;
      if (eg < cnt) {
        const int i = c * CHUNK + eg;
        const float* ae = lb + sub * 260 + e * 64;           // row-major a
        const float* qe = lb + K3_BQ + (sub >> 1) * 68 + (sub & 1) * 32 + e * 8;
        const float* pe = lb + K3_BP + (sub >> 1) * 68 + (sub & 1) * 32 + e * 8;
        const float xk  = lb[K3_BX + sub * 80 + e * 16 + k];
        float qv[8], pv[8];
        *(float4*)&qv[0] = *(const float4*)(qe);
        *(float4*)&qv[4] = *(const float4*)(qe + 4);
        *(float4*)&pv[0] = *(const float4*)(pe);
        *(float4*)&pv[4] = *(const float4*)(pe + 4);

        float y = 0.f;
#pragma unroll
        for (int m = 0; m < 8; ++m) y += pv[m] * f[m];
        out[(size_t)i * 16u + k] = y;

        float nf[8];
#pragma unroll
        for (int m = 0; m < 8; ++m) {
          float4 r0 = *(const float4*)(ae + m * 8);
          float4 r1 = *(const float4*)(ae + m * 8 + 4);
          float s = qv[m] * xk;
          s += r0.x * f[0] + r0.y * f[1] + r0.z * f[2] + r0.w * f[3]
             + r1.x * f[4] + r1.y * f[5] + r1.z * f[6] + r1.w * f[7];
          nf[m] = s;
        }
#pragma unroll
        for (int m = 0; m < 8; ++m) f[m] = nf[m];
      }
    }
  }
}

extern "C" void kernel_launch(void* const* d_in, const int* in_sizes, int n_in,
                              void* d_out, int out_size, void* d_ws, size_t ws_size,
                              hipStream_t stream)
{
  const float* p = (const float*)d_in[0];
  const float* q = (const float*)d_in[1];
  const float* a = (const float*)d_in[2];
  const float* x = (const float*)d_in[3];
  float* out = (float*)d_out;
  float* ws  = (float*)d_ws;

  hipLaunchKernelGGL(k1_aggregate, dim3(NCHUNK / 2 / 4), dim3(256), 0, stream, q, a, x, ws);
  hipLaunchKernelGGL(k2a_groupscan, dim3(NGRP), dim3(64), 0, stream, ws);
  hipLaunchKernelGGL(k2b_topscan, dim3(1), dim3(64), 0, stream, ws);
  hipLaunchKernelGGL(k3_output, dim3(NCHUNK / 4 / 4), dim3(256), 0, stream, p, q, a, x, ws, out);
}